// Round 1
// baseline (722.175 us; speedup 1.0000x reference)
//
#include <hip/hip_runtime.h>
#include <hip/hip_bf16.h>

#define FD 96          // feature dim
#define LGRID 2048     // blocks for layer kernels

// ---------------- CSR build ----------------

__global__ void k_degree(const int* __restrict__ dst, int* __restrict__ deg, int E) {
    int e = blockIdx.x * blockDim.x + threadIdx.x;
    if (e < E) atomicAdd(&deg[dst[e]], 1);
}

// wave-scan + atomic bump allocation of contiguous ranges; also inv_deg and cursor init
__global__ void k_rowptr(const int* __restrict__ deg, int* __restrict__ row_ptr,
                         int* __restrict__ cursor, float* __restrict__ inv_deg,
                         int* __restrict__ counter, int n) {
    int i = blockIdx.x * blockDim.x + threadIdx.x;
    int v = (i < n) ? deg[i] : 0;
    int lane = threadIdx.x & 63;
    // inclusive wave scan
    int incl = v;
    #pragma unroll
    for (int off = 1; off < 64; off <<= 1) {
        int t = __shfl_up(incl, off, 64);
        if (lane >= off) incl += t;
    }
    int waveTot = __shfl(incl, 63, 64);
    int base = 0;
    if (lane == 63) base = atomicAdd(counter, waveTot);
    base = __shfl(base, 63, 64);
    int excl = incl - v;
    if (i < n) {
        int start = base + excl;
        row_ptr[i] = start;
        cursor[i]  = start;
        inv_deg[i] = (v > 0) ? (1.0f / (float)v) : 0.0f;
    }
}

__global__ void k_fill(const int* __restrict__ src, const int* __restrict__ dst,
                       int* __restrict__ cursor, int* __restrict__ csr, int E) {
    int e = blockIdx.x * blockDim.x + threadIdx.x;
    if (e < E) {
        int p = atomicAdd(&cursor[dst[e]], 1);
        csr[p] = src[e];
    }
}

// ---------------- fused GIN layer ----------------
// For each node: t[f] = norm(h[node][f]) + inv_deg*sum_nbr norm(h[nbr][f]);
// out[node][o] = b[o] + sum_k t[k]*W[k][o];  optional per-column stats partials.
// block = 96 threads (thread == feature/output column). W column in registers.
template<int MODE_NORM, int STATS>
__global__ void k_layer(const float* __restrict__ hin, const float* __restrict__ W,
                        const float* __restrict__ bias,
                        const float* __restrict__ nrmA, const float* __restrict__ nrmC,
                        const int* __restrict__ row_ptr, const int* __restrict__ row_end,
                        const int* __restrict__ csr, const float* __restrict__ inv_deg,
                        float* __restrict__ hout, float* __restrict__ partials, int n) {
    __shared__ __align__(16) float t_lds[FD];
    const int f = threadIdx.x;  // 0..95
    float wcol[FD];
    #pragma unroll
    for (int k = 0; k < FD; k++) wcol[k] = W[k * FD + f];
    const float bf = bias[f];
    float na = 0.f, nc = 0.f;
    if (MODE_NORM) { na = nrmA[f]; nc = nrmC[f]; }
    float s = 0.f, s2 = 0.f;

    for (int node = blockIdx.x; node < n; node += gridDim.x) {
        const int beg = row_ptr[node];
        const int end = row_end[node];
        float xself = hin[(size_t)node * FD + f];
        if (MODE_NORM) xself = fmaxf(fmaf(na, xself, nc), 0.f);
        float acc = 0.f;
        for (int e = beg; e < end; e++) {
            int nb = csr[e];
            float x = hin[(size_t)nb * FD + f];
            if (MODE_NORM) x = fmaxf(fmaf(na, x, nc), 0.f);
            acc += x;
        }
        float t = fmaf(inv_deg[node], acc, xself);
        t_lds[f] = t;
        __syncthreads();
        float o = bf;
        #pragma unroll
        for (int k = 0; k < FD; k += 4) {
            float4 tv = *reinterpret_cast<const float4*>(&t_lds[k]);  // broadcast
            o = fmaf(tv.x, wcol[k],     o);
            o = fmaf(tv.y, wcol[k + 1], o);
            o = fmaf(tv.z, wcol[k + 2], o);
            o = fmaf(tv.w, wcol[k + 3], o);
        }
        hout[(size_t)node * FD + f] = o;
        if (STATS) { s += o; s2 = fmaf(o, o, s2); }
        __syncthreads();
    }
    if (STATS) {
        partials[(size_t)blockIdx.x * (2 * FD) + f]      = s;
        partials[(size_t)blockIdx.x * (2 * FD) + FD + f] = s2;
    }
}

// reduce per-block column partials -> BN scale/shift (a = gamma*rsqrt(var+eps), c = beta - mu*a)
__global__ void k_bnfin(const float* __restrict__ P, int G,
                        const float* __restrict__ gamma, const float* __restrict__ beta,
                        float* __restrict__ na, float* __restrict__ nc, float invN) {
    __shared__ float ls[8][FD], ls2[8][FD];
    int f = threadIdx.x, y = threadIdx.y;  // x:96, y:8
    float s = 0.f, s2 = 0.f;
    for (int g = y; g < G; g += 8) {
        s  += P[(size_t)g * (2 * FD) + f];
        s2 += P[(size_t)g * (2 * FD) + FD + f];
    }
    ls[y][f] = s; ls2[y][f] = s2;
    __syncthreads();
    if (y == 0) {
        #pragma unroll
        for (int k = 1; k < 8; k++) { s += ls[k][f]; s2 += ls2[k][f]; }
        float mu  = s * invN;
        float var = s2 * invN - mu * mu;
        float a = gamma[f] * rsqrtf(var + 1e-5f);
        na[f] = a;
        nc[f] = beta[f] - mu * a;
    }
}

extern "C" void kernel_launch(void* const* d_in, const int* in_sizes, int n_in,
                              void* d_out, int out_size, void* d_ws, size_t ws_size,
                              hipStream_t stream) {
    const float* feat = (const float*)d_in[0];
    const float* W1   = (const float*)d_in[1];
    const float* b1   = (const float*)d_in[2];
    const float* g1   = (const float*)d_in[3];
    const float* be1  = (const float*)d_in[4];
    const float* W2   = (const float*)d_in[5];
    const float* b2   = (const float*)d_in[6];
    const float* g2   = (const float*)d_in[7];
    const float* be2  = (const float*)d_in[8];
    const float* W3   = (const float*)d_in[9];
    const float* b3   = (const float*)d_in[10];
    const int*   src  = (const int*)d_in[11];
    const int*   dst  = (const int*)d_in[12];

    const int n = in_sizes[0] / FD;   // 50000
    const int e = in_sizes[11];       // 800000

    // workspace carve-up
    char* w = (char*)d_ws;
    float* hB      = (float*)w; w += (size_t)n * FD * 4;
    int*   deg     = (int*)w;   w += (size_t)n * 4;
    int*   counter = (int*)w;   w += 4;            // contiguous with deg for one memset
    int*   row_ptr = (int*)w;   w += (size_t)n * 4;
    int*   rend    = (int*)w;   w += (size_t)n * 4;  // cursor -> row end after fill
    int*   csr     = (int*)w;   w += (size_t)e * 4;
    float* invd    = (float*)w; w += (size_t)n * 4;
    float* na1     = (float*)w; w += FD * 4;
    float* nc1     = (float*)w; w += FD * 4;
    float* na2     = (float*)w; w += FD * 4;
    float* nc2     = (float*)w; w += FD * 4;
    float* partials= (float*)w; w += (size_t)LGRID * 2 * FD * 4;

    float* hA = (float*)d_out;  // layer-1 output lives in d_out, re-written by layer 3

    hipMemsetAsync(deg, 0, (size_t)(n + 1) * 4, stream);
    k_degree<<<(e + 255) / 256, 256, 0, stream>>>(dst, deg, e);
    k_rowptr<<<(n + 255) / 256, 256, 0, stream>>>(deg, row_ptr, rend, invd, counter, n);
    k_fill  <<<(e + 255) / 256, 256, 0, stream>>>(src, dst, rend, csr, e);

    // layer 1: in=features (no norm), out=hA(d_out), stats -> bn1
    k_layer<0, 1><<<LGRID, FD, 0, stream>>>(feat, W1, b1, nullptr, nullptr,
                                            row_ptr, rend, csr, invd, hA, partials, n);
    k_bnfin<<<1, dim3(FD, 8), 0, stream>>>(partials, LGRID, g1, be1, na1, nc1, 1.0f / (float)n);

    // layer 2: in=hA with relu(a1*x+c1) on reads, out=hB, stats -> bn2
    k_layer<1, 1><<<LGRID, FD, 0, stream>>>(hA, W2, b2, na1, nc1,
                                            row_ptr, rend, csr, invd, hB, partials, n);
    k_bnfin<<<1, dim3(FD, 8), 0, stream>>>(partials, LGRID, g2, be2, na2, nc2, 1.0f / (float)n);

    // layer 3: in=hB with relu(a2*x+c2) on reads, out=d_out, no stats
    k_layer<1, 0><<<LGRID, FD, 0, stream>>>(hB, W3, b3, na2, nc2,
                                            row_ptr, rend, csr, invd, (float*)d_out, partials, n);
}

// Round 2
// 389.471 us; speedup vs baseline: 1.8542x; 1.8542x over previous
//
#include <hip/hip_runtime.h>

#define FD 96
#define QD 24   // FD/4 float4s per row

// ---------------- CSR build ----------------

__global__ void k_degree(const int* __restrict__ dst, int* __restrict__ deg, int E) {
    int e = blockIdx.x * blockDim.x + threadIdx.x;
    if (e < E) atomicAdd(&deg[dst[e]], 1);
}

__global__ void k_rowptr(const int* __restrict__ deg, int* __restrict__ row_ptr,
                         int* __restrict__ cursor, float* __restrict__ inv_deg,
                         int* __restrict__ counter, int n) {
    int i = blockIdx.x * blockDim.x + threadIdx.x;
    int v = (i < n) ? deg[i] : 0;
    int lane = threadIdx.x & 63;
    int incl = v;
    #pragma unroll
    for (int off = 1; off < 64; off <<= 1) {
        int t = __shfl_up(incl, off, 64);
        if (lane >= off) incl += t;
    }
    int waveTot = __shfl(incl, 63, 64);
    int base = 0;
    if (lane == 63) base = atomicAdd(counter, waveTot);
    base = __shfl(base, 63, 64);
    int excl = incl - v;
    if (i < n) {
        int start = base + excl;
        row_ptr[i] = start;
        cursor[i]  = start;
        inv_deg[i] = (v > 0) ? (1.0f / (float)v) : 0.0f;
    }
}

__global__ void k_fill(const int* __restrict__ src, const int* __restrict__ dst,
                       int* __restrict__ cursor, int* __restrict__ csr, int E) {
    int e = blockIdx.x * blockDim.x + threadIdx.x;
    if (e < E) {
        int p = atomicAdd(&cursor[dst[e]], 1);
        csr[p] = src[e];
    }
}

// ---------------- aggregation: t = nrm(self) + inv_deg * sum nrm(nbr) ----------------

__device__ __forceinline__ float4 nrm4(float4 x, float4 a, float4 c) {
    float4 r;
    r.x = fmaxf(fmaf(a.x, x.x, c.x), 0.f);
    r.y = fmaxf(fmaf(a.y, x.y, c.y), 0.f);
    r.z = fmaxf(fmaf(a.z, x.z, c.z), 0.f);
    r.w = fmaxf(fmaf(a.w, x.w, c.w), 0.f);
    return r;
}

template<int NORM>
__global__ __launch_bounds__(256, 4) void k_agg(
    const float4* __restrict__ hin4,
    const int* __restrict__ rp, const int* __restrict__ re,
    const int* __restrict__ csr, const float* __restrict__ invd,
    const float* __restrict__ nA, const float* __restrict__ nC,
    float4* __restrict__ t4, int n)
{
    int g = blockIdx.x * blockDim.x + threadIdx.x;
    int node = g / QD;
    if (node >= n) return;
    int q = g - node * QD;
    float4 a = make_float4(0.f, 0.f, 0.f, 0.f), c = a;
    if (NORM) { a = ((const float4*)nA)[q]; c = ((const float4*)nC)[q]; }
    int e = rp[node];
    const int end = re[node];
    float ax = 0.f, ay = 0.f, az = 0.f, aw = 0.f;
    for (; e + 4 <= end; e += 4) {
        int n0 = csr[e], n1 = csr[e + 1], n2 = csr[e + 2], n3 = csr[e + 3];
        float4 x0 = hin4[(size_t)n0 * QD + q];
        float4 x1 = hin4[(size_t)n1 * QD + q];
        float4 x2 = hin4[(size_t)n2 * QD + q];
        float4 x3 = hin4[(size_t)n3 * QD + q];
        if (NORM) { x0 = nrm4(x0, a, c); x1 = nrm4(x1, a, c); x2 = nrm4(x2, a, c); x3 = nrm4(x3, a, c); }
        ax += x0.x + x1.x + x2.x + x3.x;
        ay += x0.y + x1.y + x2.y + x3.y;
        az += x0.z + x1.z + x2.z + x3.z;
        aw += x0.w + x1.w + x2.w + x3.w;
    }
    for (; e < end; e++) {
        int nb = csr[e];
        float4 x = hin4[(size_t)nb * QD + q];
        if (NORM) x = nrm4(x, a, c);
        ax += x.x; ay += x.y; az += x.z; aw += x.w;
    }
    float4 s = hin4[(size_t)node * QD + q];
    if (NORM) s = nrm4(s, a, c);
    float id = invd[node];
    float4 o;
    o.x = fmaf(id, ax, s.x);
    o.y = fmaf(id, ay, s.y);
    o.z = fmaf(id, az, s.z);
    o.w = fmaf(id, aw, s.w);
    t4[(size_t)node * QD + q] = o;
}

// ---------------- matmul: out = t @ W + b (in-place safe), optional column stats ----------------

template<int STATS>
__global__ __launch_bounds__(384, 2) void k_mm(
    const float* __restrict__ tin, const float* __restrict__ W,
    const float* __restrict__ bias, float* __restrict__ out,
    float* __restrict__ acc, int n)
{
    __shared__ __align__(16) float t_lds[4][FD + 4];
    __shared__ float r1[4][FD], r2[4][FD];
    const int tid = threadIdx.x;
    const int f = tid % FD;
    const int sub = tid / FD;   // 0..3
    float wcol[FD];
    #pragma unroll
    for (int k = 0; k < FD; k++) wcol[k] = W[k * FD + f];
    const float bf = bias[f];
    float s = 0.f, s2 = 0.f;
    const int nf = n * FD;
    for (int base = blockIdx.x * 4; base < n; base += gridDim.x * 4) {
        int idx = base * FD + tid;
        float v = (idx < nf) ? tin[idx] : 0.f;
        t_lds[sub][f] = v;
        __syncthreads();
        if (base + sub < n) {
            float o = bf;
            #pragma unroll
            for (int k = 0; k < FD; k += 4) {
                float4 tv = *reinterpret_cast<const float4*>(&t_lds[sub][k]);
                o = fmaf(tv.x, wcol[k],     o);
                o = fmaf(tv.y, wcol[k + 1], o);
                o = fmaf(tv.z, wcol[k + 2], o);
                o = fmaf(tv.w, wcol[k + 3], o);
            }
            out[(size_t)(base + sub) * FD + f] = o;
            if (STATS) { s += o; s2 = fmaf(o, o, s2); }
        }
        __syncthreads();
    }
    if (STATS) {
        r1[sub][f] = s; r2[sub][f] = s2;
        __syncthreads();
        if (sub == 0) {
            float S  = r1[0][f] + r1[1][f] + r1[2][f] + r1[3][f];
            float S2 = r2[0][f] + r2[1][f] + r2[2][f] + r2[3][f];
            atomicAdd(&acc[f], S);
            atomicAdd(&acc[FD + f], S2);
        }
    }
}

// BN constants: a = gamma*rsqrt(var+eps), c = beta - mu*a
__global__ void k_bnfin(const float* __restrict__ acc,
                        const float* __restrict__ gamma, const float* __restrict__ beta,
                        float* __restrict__ na, float* __restrict__ nc, float invN) {
    int f = threadIdx.x;
    float mu  = acc[f] * invN;
    float var = acc[FD + f] * invN - mu * mu;
    float a = gamma[f] * rsqrtf(var + 1e-5f);
    na[f] = a;
    nc[f] = beta[f] - mu * a;
}

extern "C" void kernel_launch(void* const* d_in, const int* in_sizes, int n_in,
                              void* d_out, int out_size, void* d_ws, size_t ws_size,
                              hipStream_t stream) {
    const float* feat = (const float*)d_in[0];
    const float* W1   = (const float*)d_in[1];
    const float* b1   = (const float*)d_in[2];
    const float* g1   = (const float*)d_in[3];
    const float* be1  = (const float*)d_in[4];
    const float* W2   = (const float*)d_in[5];
    const float* b2   = (const float*)d_in[6];
    const float* g2   = (const float*)d_in[7];
    const float* be2  = (const float*)d_in[8];
    const float* W3   = (const float*)d_in[9];
    const float* b3   = (const float*)d_in[10];
    const int*   src  = (const int*)d_in[11];
    const int*   dst  = (const int*)d_in[12];

    const int n = in_sizes[0] / FD;   // 50000
    const int e = in_sizes[11];       // 800000

    char* w = (char*)d_ws;
    float* A       = (float*)w; w += (size_t)n * FD * 4;
    int*   deg     = (int*)w;   w += (size_t)n * 4;
    int*   counter = (int*)w;   w += 4;
    float* acc1    = (float*)w; w += 2 * FD * 4;   // contiguous with deg for one memset
    float* acc2    = (float*)w; w += 2 * FD * 4;
    int*   rp      = (int*)w;   w += (size_t)n * 4;
    int*   re      = (int*)w;   w += (size_t)n * 4;
    int*   csr     = (int*)w;   w += (size_t)e * 4;
    float* invd    = (float*)w; w += (size_t)n * 4;
    float* na1     = (float*)w; w += FD * 4;
    float* nc1     = (float*)w; w += FD * 4;
    float* na2     = (float*)w; w += FD * 4;
    float* nc2     = (float*)w; w += FD * 4;

    float* O = (float*)d_out;
    const float invN = 1.0f / (float)n;
    const int AGG_GRID = (n * QD + 255) / 256;

    hipMemsetAsync(deg, 0, (size_t)(n + 1 + 4 * FD) * 4, stream);
    k_degree<<<(e + 255) / 256, 256, 0, stream>>>(dst, deg, e);
    k_rowptr<<<(n + 255) / 256, 256, 0, stream>>>(deg, rp, re, invd, counter, n);
    k_fill  <<<(e + 255) / 256, 256, 0, stream>>>(src, dst, re, csr, e);

    // layer 1
    k_agg<0><<<AGG_GRID, 256, 0, stream>>>((const float4*)feat, rp, re, csr, invd,
                                           nullptr, nullptr, (float4*)A, n);
    k_mm<1><<<1024, 384, 0, stream>>>(A, W1, b1, A, acc1, n);
    k_bnfin<<<1, FD, 0, stream>>>(acc1, g1, be1, na1, nc1, invN);

    // layer 2
    k_agg<1><<<AGG_GRID, 256, 0, stream>>>((const float4*)A, rp, re, csr, invd,
                                           na1, nc1, (float4*)O, n);
    k_mm<1><<<1024, 384, 0, stream>>>(O, W2, b2, O, acc2, n);
    k_bnfin<<<1, FD, 0, stream>>>(acc2, g2, be2, na2, nc2, invN);

    // layer 3
    k_agg<1><<<AGG_GRID, 256, 0, stream>>>((const float4*)O, rp, re, csr, invd,
                                           na2, nc2, (float4*)A, n);
    k_mm<0><<<1024, 384, 0, stream>>>(A, W3, b3, O, nullptr, n);
}